// Round 3
// baseline (417.391 us; speedup 1.0000x reference)
//
#include <hip/hip_runtime.h>
#include <math.h>

#define NMAX 64
#define JITTER 1e-5

// Broadcast one lane's fp64 register to all lanes via v_readlane (SGPR pair).
// `lane` must be wave-uniform (here: compile-time constants from full unroll).
__device__ __forceinline__ double rdlane_f64(double x, int lane) {
    union { double d; int i[2]; } a, r;
    a.d = x;
    r.i[0] = __builtin_amdgcn_readlane(a.i[0], lane);
    r.i[1] = __builtin_amdgcn_readlane(a.i[1], lane);
    return r.d;
}

// One 64-thread (single-wave) block per (batch, variable) pair.
// Register-resident factorization: lane i owns row i of C (Cholesky of Kn),
// lane j owns column j of Kxx (in-place forward solve). Cross-lane operands
// are lane-invariant -> v_readlane broadcasts, zero LDS in the hot loops.
// All math fp64 (mask output is hard 0/1; keep the proven-passing numerics).
__global__ __launch_bounds__(64)
void gp_mask_kernel(const float* __restrict__ t,      // [B,L]
                    const int*   __restrict__ vid,    // [B,L]
                    const float* __restrict__ noise,  // [V]
                    const float* __restrict__ outscale,
                    const float* __restrict__ lscale,
                    const float* __restrict__ alpha,
                    const int*   __restrict__ pK,     // hyper_num_nodes
                    float* __restrict__ out_mask,     // [B,L,V*K]
                    float* __restrict__ out_gains,    // [B,L]
                    int B, int L, int V)
{
    const int b = blockIdx.x / V;
    const int v = blockIdx.x % V;
    const int tid = threadIdx.x;
    const int Knodes = pK[0];
    const int VK = V * Knodes;

    __shared__ double Klds[NMAX][NMAX + 1];  // Kxx staging; reused as std staging
    __shared__ double ts[NMAX];
    __shared__ float  tu[NMAX];
    __shared__ int    idx_u[NMAX];
    __shared__ int    oidx[NMAX];
    __shared__ int    cnt;

    // Zero this block's exclusively-owned mask slab: [b, :, v*K .. v*K+K)
    for (int p = tid; p < L; p += 64) {
        float* dst = out_mask + ((size_t)b * L + p) * VK + v * Knodes;
        for (int g = 0; g < Knodes; g++) dst[g] = 0.0f;
    }

    if (tid == 0) cnt = 0;
    __syncthreads();

    // Collect this variable's points (order nondeterministic; sorted next).
    for (int i = tid; i < L; i += 64) {
        if (vid[b * L + i] == v) {
            int p = atomicAdd(&cnt, 1);
            if (p < NMAX) { idx_u[p] = i; tu[p] = t[b * L + i]; }
        }
    }
    __syncthreads();
    int n = __builtin_amdgcn_readfirstlane(cnt);   // force SGPR -> scalar branches
    if (n > NMAX) n = NMAX;

    // Stable rank sort by (t, original index) — matches jnp.argsort semantics.
    if (tid < n) {
        float tv = tu[tid]; int iv = idx_u[tid];
        int r = 0;
        for (int e = 0; e < n; e++) {
            float te = tu[e]; int ie = idx_u[e];
            if (te < tv || (te == tv && ie < iv)) r++;
        }
        ts[r] = (double)tv;
        oidx[r] = iv;
    }
    __syncthreads();

    const double os_ = (double)outscale[v];
    const double nz  = (double)noise[v];
    const double ls  = (double)lscale[v];
    const double al  = (double)alpha[v];
    const double isc = 1.0 / (2.0 * al * ls * ls);

    // Zero Kxx staging, then fill strict lower triangle (+ mirror) with RQ
    // values, flattened across all 64 lanes (~n(n-1)/128 pow calls per lane).
    for (int q = tid; q < NMAX * (NMAX + 1); q += 64)
        ((double*)Klds)[q] = 0.0;
    __syncthreads();
    {
        const int P = n * (n - 1) / 2;
        for (int e = tid; e < P; e += 64) {
            int i = (int)((sqrt(8.0 * (double)e + 1.0) + 1.0) * 0.5);
            while (i * (i - 1) / 2 > e) --i;
            while ((i + 1) * i / 2 <= e) ++i;
            int j = e - i * (i - 1) / 2;
            double d = ts[i] - ts[j];
            double val = os_ * pow(1.0 + d * d * isc, -al);
            Klds[i][j] = val;
            Klds[j][i] = val;
        }
    }
    __syncthreads();

    const bool live = tid < n;

    // Lane tid's row of Kn (dead rows = identity: matches reference padding).
    double c[NMAX];
    {
        const double cdiag = live ? (os_ + nz + JITTER) : 1.0;
        #pragma unroll
        for (int j = 0; j < NMAX; j++)
            c[j] = (j == tid) ? cdiag : Klds[tid][j];
    }

    // In-register right-looking Cholesky. At step k:
    //   d = sqrt(C[k][k]);  L[i][k] = c[k]*inv (lane-local);
    //   lane k's c[k] stores inv(d) (only ever read as the solve's 1/crr);
    //   update c[j] -= c[k] * readlane(c[k], j)  — pure readlane+FMA.
    // Lanes' upper-triangle entries become garbage but are never read.
    #pragma unroll
    for (int k = 0; k < NMAX; k++) {
        if (k >= n) break;
        double dkk = rdlane_f64(c[k], k);
        double sd  = sqrt(dkk);
        double inv = 1.0 / sd;
        double scaled = c[k] * inv;
        c[k] = (tid == k) ? inv : scaled;
        #pragma unroll
        for (int j = k + 1; j < NMAX; j++) {
            if (j >= n) break;
            double ljk = rdlane_f64(c[k], j);
            c[j] -= c[k] * ljk;
        }
    }

    // Lane tid's column of Kxx (loaded after chol to cap register pressure).
    double kx[NMAX];
    {
        const double kdiag = live ? os_ : 0.0;
        #pragma unroll
        for (int i = 0; i < NMAX; i++)
            kx[i] = (i == tid) ? kdiag : Klds[i][tid];
    }

    // Forward solve C*V = Kxx in place on kx (lane = column), prefix variance,
    // std staged into the now-dead Klds rows (transpose-reduced afterwards).
    {
        double cum = 0.0;
        #pragma unroll
        for (int r = 0; r < NMAX; r++) {
            if (r >= n) break;
            double invc = rdlane_f64(c[r], r);        // = 1/C[r][r]
            double vv = kx[r] * invc;
            cum += vv * vv;
            double var = os_ - cum;
            double stdv = sqrt(var > 1e-12 ? var : 1e-12);
            Klds[r][tid] = live ? stdv : 0.0;         // mf mask on columns
            #pragma unroll
            for (int i = r + 1; i < NMAX; i++) {
                if (i >= n) break;
                double cir = rdlane_f64(c[r], i);     // C[i][r]
                kx[i] -= cir * vv;
            }
        }
    }
    __syncthreads();

    // sums[r] = row-sum of staged std; lane r owns sums[r].
    double s_mine = 0.0;
    for (int j = 0; j < NMAX; j++) s_mine += Klds[tid][j];

    // Gains + wave prefix-scan for cumulative gain, then group + scatter.
    if (n > 0) {
        double sprev = __shfl(s_mine, (tid == 0) ? 0 : tid - 1, 64);
        double prev  = (tid == 0) ? sqrt(os_) * (double)n : sprev;
        double g = 0.0;
        if (live) {
            g = prev - s_mine;
            if (g < 0.0) g = 0.0;
        }
        double sc = g;                                // inclusive prefix sum
        #pragma unroll
        for (int off = 1; off < 64; off <<= 1) {
            double o = __shfl_up(sc, off, 64);
            if (tid >= off) sc += o;
        }
        double total = __shfl(sc, n - 1, 64);
        if (live) {
            double denom = total > 1e-12 ? total : 1e-12;
            double frac = (sc - 0.5 * g) / denom;
            int grp = (int)floor(frac * (double)Knodes);
            if (grp < 0) grp = 0;
            if (grp > Knodes - 1) grp = Knodes - 1;
            int p = oidx[tid];
            out_mask[((size_t)b * L + p) * VK + v * Knodes + grp] = 1.0f;
            out_gains[(size_t)b * L + p] = (float)g;
        }
    }
}

extern "C" void kernel_launch(void* const* d_in, const int* in_sizes, int n_in,
                              void* d_out, int out_size, void* d_ws, size_t ws_size,
                              hipStream_t stream)
{
    const float* t     = (const float*)d_in[0];
    // d_in[1] = y: posterior variance is y-independent; unused.
    const int*   vid   = (const int*)d_in[2];
    const float* noise = (const float*)d_in[3];
    const float* osc   = (const float*)d_in[4];
    const float* ls    = (const float*)d_in[5];
    const float* al    = (const float*)d_in[6];
    const int*   pK    = (const int*)d_in[7];

    const int V = in_sizes[3];          // 16
    const int L = 512;                  // per reference setup
    const int B = in_sizes[0] / L;      // 8

    float* out_mask  = (float*)d_out;
    float* out_gains = (float*)d_out + ((size_t)out_size - (size_t)B * L);

    gp_mask_kernel<<<B * V, 64, 0, stream>>>(t, vid, noise, osc, ls, al, pK,
                                             out_mask, out_gains, B, L, V);
}

// Round 4
// 124.401 us; speedup vs baseline: 3.3552x; 3.3552x over previous
//
#include <hip/hip_runtime.h>
#include <math.h>

#define NMAX 64
#define JITTER 1e-5

// Broadcast one lane's fp64 register to all lanes via v_readlane (SGPR pair).
// Lane index is a compile-time constant (full unroll) -> pure scalar broadcast,
// no LDS traffic.
__device__ __forceinline__ double rdlane_f64(double x, int lane) {
    union { double d; int i[2]; } a, r;
    a.d = x;
    r.i[0] = __builtin_amdgcn_readlane(a.i[0], lane);
    r.i[1] = __builtin_amdgcn_readlane(a.i[1], lane);
    return r.d;
}

// One 64-thread (single-wave) block per (batch, variable) pair.
// Register-resident fused Cholesky + forward solve:
//   lane i owns row i of C (Cholesky of Kn)   -> c[64]  (128 VGPR)
//   lane j owns column j of Kxx (in-place V)  -> kx[64] (128 VGPR)
// Cross-lane operands are readlane broadcasts. Trip counts are FIXED at 64
// (identity padding == reference's masked-point padding), so every loop fully
// unrolls and every array index is static => true register residency.
// __launch_bounds__(64, 1): 1 wave/SIMD floor -> 512-VGPR budget, no spill.
// All math fp64 (mask output is hard 0/1; keep proven-passing numerics).
__global__ __launch_bounds__(64, 1)
void gp_mask_kernel(const float* __restrict__ t,      // [B,L]
                    const int*   __restrict__ vid,    // [B,L]
                    const float* __restrict__ noise,  // [V]
                    const float* __restrict__ outscale,
                    const float* __restrict__ lscale,
                    const float* __restrict__ alpha,
                    const int*   __restrict__ pK,     // hyper_num_nodes
                    float* __restrict__ out_mask,     // [B,L,V*K]
                    float* __restrict__ out_gains,    // [B,L]
                    int B, int L, int V)
{
    const int b = blockIdx.x / V;
    const int v = blockIdx.x % V;
    const int tid = threadIdx.x;
    const int Knodes = pK[0];
    const int VK = V * Knodes;

    __shared__ double Klds[NMAX][NMAX + 1];  // Kxx staging; reused as std staging
    __shared__ double ts[NMAX];
    __shared__ float  tu[NMAX];
    __shared__ int    idx_u[NMAX];
    __shared__ int    oidx[NMAX];
    __shared__ int    cnt;

    // Zero this block's exclusively-owned mask slab: [b, :, v*K .. v*K+K)
    // (coalesced: consecutive lanes -> consecutive floats within a row chunk)
    for (int q = tid; q < L * Knodes; q += 64) {
        int p = q / Knodes, g = q - p * Knodes;
        out_mask[((size_t)b * L + p) * VK + v * Knodes + g] = 0.0f;
    }

    if (tid == 0) cnt = 0;
    __syncthreads();

    // Collect this variable's points (order nondeterministic; sorted next).
    for (int i = tid; i < L; i += 64) {
        if (vid[b * L + i] == v) {
            int p = atomicAdd(&cnt, 1);
            if (p < NMAX) { idx_u[p] = i; tu[p] = t[b * L + i]; }
        }
    }
    __syncthreads();
    int n = __builtin_amdgcn_readfirstlane(cnt);
    if (n > NMAX) n = NMAX;

    // Stable rank sort by (t, original index) — matches jnp.argsort semantics.
    if (tid < n) {
        float tv = tu[tid]; int iv = idx_u[tid];
        int r = 0;
        for (int e = 0; e < n; e++) {
            float te = tu[e]; int ie = idx_u[e];
            if (te < tv || (te == tv && ie < iv)) r++;
        }
        ts[r] = (double)tv;
        oidx[r] = iv;
    }
    __syncthreads();

    const double os_ = (double)outscale[v];
    const double nz  = (double)noise[v];
    const double ls  = (double)lscale[v];
    const double al  = (double)alpha[v];
    const double isc = 1.0 / (2.0 * al * ls * ls);

    // Zero Kxx staging, then fill strict lower triangle (+ mirror) with RQ
    // values flattened across all 64 lanes (~n(n-1)/128 pow calls per lane).
    // Rows/cols >= n stay zero => identity-padded system (reference semantics).
    for (int q = tid; q < NMAX * (NMAX + 1); q += 64)
        ((double*)Klds)[q] = 0.0;
    __syncthreads();
    {
        const int P = n * (n - 1) / 2;
        for (int e = tid; e < P; e += 64) {
            int i = (int)((sqrt(8.0 * (double)e + 1.0) + 1.0) * 0.5);
            while (i * (i - 1) / 2 > e) --i;
            while ((i + 1) * i / 2 <= e) ++i;
            int j = e - i * (i - 1) / 2;
            double d = ts[i] - ts[j];
            double val = os_ * pow(1.0 + d * d * isc, -al);
            Klds[i][j] = val;
            Klds[j][i] = val;
        }
    }
    __syncthreads();

    const bool live = tid < n;

    // Load register rows/columns (static indices only).
    double c[NMAX];   // lane tid: row tid of Kn (identity for dead lanes)
    double kx[NMAX];  // lane tid: column tid of Kxx (zero for dead lanes)
    {
        const double cdiag = live ? (os_ + nz + JITTER) : 1.0;
        const double kdiag = live ? os_ : 0.0;
        #pragma unroll
        for (int j = 0; j < NMAX; j++) {
            c[j]  = (j == tid) ? cdiag : Klds[tid][j];
            kx[j] = (j == tid) ? kdiag : Klds[j][tid];
        }
    }
    __syncthreads();   // Klds is re-purposed as std staging below

    // Fused right-looking Cholesky + forward solve, fixed 64 steps.
    // Step k: factor column k, immediately consume it for solve row k.
    // The broadcast L[j][k] serves BOTH the trailing update and the solve.
    {
        double cum = 0.0;
        #pragma unroll
        for (int k = 0; k < NMAX; k++) {
            double dkk = rdlane_f64(c[k], k);   // C[k][k] before scaling
            double inv = 1.0 / sqrt(dkk);
            c[k] *= inv;                        // lane tid: L[tid][k] (tid>k valid)
            double vv = kx[k] * inv;            // solve row k, own column
            cum += vv * vv;
            double var = os_ - cum;
            double stdv = sqrt(var > 1e-12 ? var : 1e-12);
            Klds[k][tid] = live ? stdv : 0.0;   // std_pref[k][col], mf-masked
            #pragma unroll
            for (int j = k + 1; j < NMAX; j++) {
                double ljk = rdlane_f64(c[k], j);   // L[j][k]
                c[j]  -= c[k] * ljk;                // trailing-matrix update
                kx[j] -= ljk * vv;                  // solve forward-substitution
            }
        }
    }
    __syncthreads();

    // sums[r] = row-sum of staged std; lane r owns sums[r].
    double s_mine = 0.0;
    for (int j = 0; j < NMAX; j++) s_mine += Klds[tid][j];

    // Gains + wave prefix-scan for cumulative gain, then group + scatter.
    if (n > 0) {
        double sprev = __shfl(s_mine, (tid == 0) ? 0 : tid - 1, 64);
        double prev  = (tid == 0) ? sqrt(os_) * (double)n : sprev;
        double g = 0.0;
        if (live) {
            g = prev - s_mine;
            if (g < 0.0) g = 0.0;
        }
        double sc = g;                                // inclusive prefix sum
        #pragma unroll
        for (int off = 1; off < 64; off <<= 1) {
            double o = __shfl_up(sc, off, 64);
            if (tid >= off) sc += o;
        }
        double total = __shfl(sc, n - 1, 64);
        if (live) {
            double denom = total > 1e-12 ? total : 1e-12;
            double frac = (sc - 0.5 * g) / denom;
            int grp = (int)floor(frac * (double)Knodes);
            if (grp < 0) grp = 0;
            if (grp > Knodes - 1) grp = Knodes - 1;
            int p = oidx[tid];
            out_mask[((size_t)b * L + p) * VK + v * Knodes + grp] = 1.0f;
            out_gains[(size_t)b * L + p] = (float)g;
        }
    }
}

extern "C" void kernel_launch(void* const* d_in, const int* in_sizes, int n_in,
                              void* d_out, int out_size, void* d_ws, size_t ws_size,
                              hipStream_t stream)
{
    const float* t     = (const float*)d_in[0];
    // d_in[1] = y: posterior variance is y-independent; unused.
    const int*   vid   = (const int*)d_in[2];
    const float* noise = (const float*)d_in[3];
    const float* osc   = (const float*)d_in[4];
    const float* ls    = (const float*)d_in[5];
    const float* al    = (const float*)d_in[6];
    const int*   pK    = (const int*)d_in[7];

    const int V = in_sizes[3];          // 16
    const int L = 512;                  // per reference setup
    const int B = in_sizes[0] / L;      // 8

    float* out_mask  = (float*)d_out;
    float* out_gains = (float*)d_out + ((size_t)out_size - (size_t)B * L);

    gp_mask_kernel<<<B * V, 64, 0, stream>>>(t, vid, noise, osc, ls, al, pK,
                                             out_mask, out_gains, B, L, V);
}

// Round 5
// 121.755 us; speedup vs baseline: 3.4281x; 1.0217x over previous
//
#include <hip/hip_runtime.h>
#include <math.h>

#define NMAX 64
#define JITTER 1e-5

// ---- compile-time integer sequences (hand-rolled; no <utility> in device) ----
template<int...> struct iseq {};
template<int N, int... Is> struct mkseq : mkseq<N - 1, N - 1, Is...> {};
template<int... Is> struct mkseq<0, Is...> { using type = iseq<Is...>; };
template<int N> using mkseq_t = typename mkseq<N>::type;

// Broadcast one lane's fp64 register to all lanes via v_readlane (SGPR pair).
// Lane index is a compile-time constant here -> pure scalar broadcast.
__device__ __forceinline__ double rdlane_f64(double x, int lane) {
    union { double d; int i[2]; } a, r;
    a.d = x;
    r.i[0] = __builtin_amdgcn_readlane(a.i[0], lane);
    r.i[1] = __builtin_amdgcn_readlane(a.i[1], lane);
    return r.d;
}

// ---- register load: c[J], kx[J] with constexpr J (SROA-promotable GEPs) ----
template<int J>
__device__ __forceinline__ void load_one(double (&c)[NMAX], double (&kx)[NMAX],
                                         const double (&Klds)[NMAX][NMAX + 1],
                                         int tid, double cdiag, double kdiag) {
    c[J]  = (J == tid) ? cdiag : Klds[tid][J];
    kx[J] = (J == tid) ? kdiag : Klds[J][tid];
}
template<int... Js>
__device__ __forceinline__ void load_all(iseq<Js...>, double (&c)[NMAX], double (&kx)[NMAX],
                                         const double (&Klds)[NMAX][NMAX + 1],
                                         int tid, double cdiag, double kdiag) {
    (load_one<Js>(c, kx, Klds, tid, cdiag, kdiag), ...);
}

// ---- fused Cholesky + forward-solve inner body, constexpr K,J ----
template<int K, int J>
__device__ __forceinline__ void inner_one(double (&c)[NMAX], double (&kx)[NMAX], double vv) {
    double ljk = rdlane_f64(c[K], J);   // L[J][K] broadcast from lane J
    c[J]  -= c[K] * ljk;                // trailing-matrix update (Cholesky)
    kx[J] -= ljk * vv;                  // forward substitution (solve)
}
template<int K, int... Js>
__device__ __forceinline__ void inner_all(iseq<Js...>, double (&c)[NMAX], double (&kx)[NMAX],
                                          double vv) {
    (inner_one<K, K + 1 + Js>(c, kx, vv), ...);
}

template<int K>
__device__ __forceinline__ void step_one(double (&c)[NMAX], double (&kx)[NMAX],
                                         double& cum, double os_, bool live,
                                         double (&Klds)[NMAX][NMAX + 1], int tid) {
    double dkk = rdlane_f64(c[K], K);   // C[K][K] before scaling
    double inv = 1.0 / sqrt(dkk);
    c[K] *= inv;                        // lane tid: L[tid][K] (tid>K valid)
    double vv = kx[K] * inv;            // solve row K, own column
    cum += vv * vv;
    double var = os_ - cum;
    double stdv = sqrt(var > 1e-12 ? var : 1e-12);
    Klds[K][tid] = live ? stdv : 0.0;   // std_pref[K][col], mf-masked
    inner_all<K>(mkseq_t<NMAX - 1 - K>{}, c, kx, vv);
}
template<int... Ks>
__device__ __forceinline__ void steps_all(iseq<Ks...>, double (&c)[NMAX], double (&kx)[NMAX],
                                          double& cum, double os_, bool live,
                                          double (&Klds)[NMAX][NMAX + 1], int tid) {
    (step_one<Ks>(c, kx, cum, os_, live, Klds, tid), ...);
}

// One 64-thread (single-wave) block per (batch, variable) pair.
// Register-resident fused Cholesky + forward solve; all indices constexpr via
// template expansion => SROA promotes c[]/kx[] to VGPRs regardless of loop
// unroll heuristics (R4 failed here: VGPR=148 proved allocas went to scratch).
// Fixed 64 steps with identity padding == reference's masked-point semantics.
// All math fp64 (mask output is hard 0/1; keep proven-passing numerics).
__global__ __launch_bounds__(64, 1)
void gp_mask_kernel(const float* __restrict__ t,      // [B,L]
                    const int*   __restrict__ vid,    // [B,L]
                    const float* __restrict__ noise,  // [V]
                    const float* __restrict__ outscale,
                    const float* __restrict__ lscale,
                    const float* __restrict__ alpha,
                    const int*   __restrict__ pK,     // hyper_num_nodes
                    float* __restrict__ out_mask,     // [B,L,V*K]
                    float* __restrict__ out_gains,    // [B,L]
                    int B, int L, int V)
{
    const int b = blockIdx.x / V;
    const int v = blockIdx.x % V;
    const int tid = threadIdx.x;
    const int Knodes = pK[0];
    const int VK = V * Knodes;

    __shared__ double Klds[NMAX][NMAX + 1];  // Kxx staging; reused as std staging
    __shared__ double ts[NMAX];
    __shared__ float  tu[NMAX];
    __shared__ int    idx_u[NMAX];
    __shared__ int    oidx[NMAX];
    __shared__ int    cnt;

    // Zero this block's exclusively-owned mask slab: [b, :, v*K .. v*K+K)
    if ((Knodes & 3) == 0) {
        const int kq = Knodes >> 2;          // float4 chunks per row
        const float4 z = make_float4(0.f, 0.f, 0.f, 0.f);
        for (int q = tid; q < L * kq; q += 64) {
            int p = q / kq, g = q - p * kq;
            float4* dst = (float4*)(out_mask + ((size_t)b * L + p) * VK + v * Knodes) + g;
            *dst = z;
        }
    } else {
        for (int q = tid; q < L * Knodes; q += 64) {
            int p = q / Knodes, g = q - p * Knodes;
            out_mask[((size_t)b * L + p) * VK + v * Knodes + g] = 0.0f;
        }
    }

    if (tid == 0) cnt = 0;
    __syncthreads();

    // Collect this variable's points (order nondeterministic; sorted next).
    for (int i = tid; i < L; i += 64) {
        if (vid[b * L + i] == v) {
            int p = atomicAdd(&cnt, 1);
            if (p < NMAX) { idx_u[p] = i; tu[p] = t[b * L + i]; }
        }
    }
    __syncthreads();
    int n = __builtin_amdgcn_readfirstlane(cnt);
    if (n > NMAX) n = NMAX;

    // Stable rank sort by (t, original index) — matches jnp.argsort semantics.
    if (tid < n) {
        float tv = tu[tid]; int iv = idx_u[tid];
        int r = 0;
        for (int e = 0; e < n; e++) {
            float te = tu[e]; int ie = idx_u[e];
            if (te < tv || (te == tv && ie < iv)) r++;
        }
        ts[r] = (double)tv;
        oidx[r] = iv;
    }
    __syncthreads();

    const double os_ = (double)outscale[v];
    const double nz  = (double)noise[v];
    const double ls  = (double)lscale[v];
    const double al  = (double)alpha[v];
    const double isc = 1.0 / (2.0 * al * ls * ls);

    // Zero Kxx staging, then fill strict lower triangle (+ mirror) with RQ
    // values flattened across all 64 lanes (~n(n-1)/128 pow calls per lane).
    // Rows/cols >= n stay zero => identity-padded system (reference semantics).
    for (int q = tid; q < NMAX * (NMAX + 1); q += 64)
        ((double*)Klds)[q] = 0.0;
    __syncthreads();
    {
        const int P = n * (n - 1) / 2;
        for (int e = tid; e < P; e += 64) {
            int i = (int)((sqrt(8.0 * (double)e + 1.0) + 1.0) * 0.5);
            while (i * (i - 1) / 2 > e) --i;
            while ((i + 1) * i / 2 <= e) ++i;
            int j = e - i * (i - 1) / 2;
            double d = ts[i] - ts[j];
            double val = os_ * pow(1.0 + d * d * isc, -al);
            Klds[i][j] = val;
            Klds[j][i] = val;
        }
    }
    __syncthreads();

    const bool live = tid < n;

    // Register rows/columns via constexpr-index template expansion.
    double c[NMAX];   // lane tid: row tid of Kn (identity for dead lanes)
    double kx[NMAX];  // lane tid: column tid of Kxx (zero for dead lanes)
    {
        const double cdiag = live ? (os_ + nz + JITTER) : 1.0;
        const double kdiag = live ? os_ : 0.0;
        load_all(mkseq_t<NMAX>{}, c, kx, Klds, tid, cdiag, kdiag);
    }
    __syncthreads();   // Klds is re-purposed as std staging below

    // Fused right-looking Cholesky + forward solve, 64 straight-line steps.
    {
        double cum = 0.0;
        steps_all(mkseq_t<NMAX>{}, c, kx, cum, os_, live, Klds, tid);
    }
    __syncthreads();

    // sums[r] = row-sum of staged std; lane r owns sums[r].
    double s_mine = 0.0;
    for (int j = 0; j < NMAX; j++) s_mine += Klds[tid][j];

    // Gains + wave prefix-scan for cumulative gain, then group + scatter.
    if (n > 0) {
        double sprev = __shfl(s_mine, (tid == 0) ? 0 : tid - 1, 64);
        double prev  = (tid == 0) ? sqrt(os_) * (double)n : sprev;
        double g = 0.0;
        if (live) {
            g = prev - s_mine;
            if (g < 0.0) g = 0.0;
        }
        double sc = g;                                // inclusive prefix sum
        #pragma unroll
        for (int off = 1; off < 64; off <<= 1) {
            double o = __shfl_up(sc, off, 64);
            if (tid >= off) sc += o;
        }
        double total = __shfl(sc, n - 1, 64);
        if (live) {
            double denom = total > 1e-12 ? total : 1e-12;
            double frac = (sc - 0.5 * g) / denom;
            int grp = (int)floor(frac * (double)Knodes);
            if (grp < 0) grp = 0;
            if (grp > Knodes - 1) grp = Knodes - 1;
            int p = oidx[tid];
            out_mask[((size_t)b * L + p) * VK + v * Knodes + grp] = 1.0f;
            out_gains[(size_t)b * L + p] = (float)g;
        }
    }
}

extern "C" void kernel_launch(void* const* d_in, const int* in_sizes, int n_in,
                              void* d_out, int out_size, void* d_ws, size_t ws_size,
                              hipStream_t stream)
{
    const float* t     = (const float*)d_in[0];
    // d_in[1] = y: posterior variance is y-independent; unused.
    const int*   vid   = (const int*)d_in[2];
    const float* noise = (const float*)d_in[3];
    const float* osc   = (const float*)d_in[4];
    const float* ls    = (const float*)d_in[5];
    const float* al    = (const float*)d_in[6];
    const int*   pK    = (const int*)d_in[7];

    const int V = in_sizes[3];          // 16
    const int L = 512;                  // per reference setup
    const int B = in_sizes[0] / L;      // 8

    float* out_mask  = (float*)d_out;
    float* out_gains = (float*)d_out + ((size_t)out_size - (size_t)B * L);

    gp_mask_kernel<<<B * V, 64, 0, stream>>>(t, vid, noise, osc, ls, al, pK,
                                             out_mask, out_gains, B, L, V);
}